// Round 9
// baseline (235.753 us; speedup 1.0000x reference)
//
#include <hip/hip_runtime.h>
#include <hip/hip_bf16.h>

// SubjectLayers via bf16 MFMA 32x32x16: out[b,o,t] = sum_c W[s,o,c]*x[b,c,t] + b[s,o]
// B=128, C=64, T=8192, S=16. fp32 in/out, bf16 matrix cores.
//
// R8 = R6 (TT=256, 1KB-burst staging both directions — best known, 105.3us)
//      + persistent blocks (8 consecutive tiles each) with register prefetch:
//   - loads for tile k+1 issued before compute of tile k -> in flight across
//     the whole compute+store phase (~7k cyc >> 900 cyc HBM latency)
//   - stores of k overlap loads of k+1 (independent vmem streams)
//   - W/bias fragments loaded once per block, not per tile
//   - LDS unpadded [64][256] = 64KB, 2 blocks/CU; bank-audit: frag reads and
//     epilogue writes 2-way (free), staging/readback b128 structural-optimal.
//   - per-wave row sets disjoint; store-readback then x-rewrite of the same
//     rows are same-wave ordered DS ops -> no extra barrier needed.

typedef __attribute__((ext_vector_type(8))) short  bf16x8;   // 4 VGPRs
typedef __attribute__((ext_vector_type(16))) float f32x16;   // 16 VGPRs

namespace {
constexpr int Cdim  = 64;
constexpr int Tdim  = 8192;
constexpr int TT    = 256;        // t per tile
constexpr int TILES = 8;          // consecutive tiles per block
constexpr int BLOCK = 256;        // 4 waves
}

static __device__ __forceinline__ short f2bf(float f) {
    return (short)__builtin_bit_cast(unsigned short, __float2bfloat16(f));
}

__global__ __launch_bounds__(BLOCK, 2)
void subject_layers_r8(const float* __restrict__ x,
                       const int*   __restrict__ subj,
                       const float* __restrict__ W,
                       const float* __restrict__ bias,
                       float*       __restrict__ out) {
    __shared__ float tile[Cdim * TT];   // 65536 B; x-tile, reused as out-tile

    const int b    = blockIdx.y;
    const int tg   = blockIdx.x;        // tile group (8 consecutive tiles)
    const int tid  = threadIdx.x;
    const int wave = tid >> 6;
    const int lane = tid & 63;
    const int hi   = lane >> 5;   // 0..1
    const int ln   = lane & 31;   // m/n index within 32-tile
    const int s    = subj[b];

    const size_t bbase  = (size_t)b * Cdim * Tdim;
    const size_t tstart = (size_t)tg * (TILES * TT);

    // ---- A fragments: W[s] -> bf16 (once per block) ----
    // A[m][k]: m = ln, k = kb*16 + hi*8 + j  (mirrored with B -> k-perm cancels)
    bf16x8 afrag[2][4];
    const float* Wb = W + (size_t)s * Cdim * Cdim;
    #pragma unroll
    for (int ot = 0; ot < 2; ++ot) {
        #pragma unroll
        for (int kb = 0; kb < 4; ++kb) {
            const float* ap = Wb + (size_t)(ot * 32 + ln) * Cdim + kb * 16 + hi * 8;
            const float4 a0 = *reinterpret_cast<const float4*>(ap);
            const float4 a1 = *reinterpret_cast<const float4*>(ap + 4);
            bf16x8 f;
            f[0] = f2bf(a0.x); f[1] = f2bf(a0.y); f[2] = f2bf(a0.z); f[3] = f2bf(a0.w);
            f[4] = f2bf(a1.x); f[5] = f2bf(a1.y); f[6] = f2bf(a1.z); f[7] = f2bf(a1.w);
            afrag[ot][kb] = f;
        }
    }

    // ---- bias -> accumulator init ----
    // C/D: col = ln, row(reg r) = (r&3) + 8*(r>>2) + 4*hi   [m74/m101-verified]
    f32x16 bini[2];
    const float* bb = bias + (size_t)s * Cdim;
    #pragma unroll
    for (int ot = 0; ot < 2; ++ot)
        #pragma unroll
        for (int r = 0; r < 16; ++r)
            bini[ot][r] = bb[ot * 32 + (r & 3) + 8 * (r >> 2) + 4 * hi];

    // ---- prologue: stage tile 0 (1KB-row bursts: wave w owns rows g*4+w) ----
    float4 v[16];
    #pragma unroll
    for (int g = 0; g < 16; ++g) {
        const int row = g * 4 + wave;
        v[g] = *reinterpret_cast<const float4*>(
            x + bbase + tstart + (size_t)row * Tdim + lane * 4);
    }
    #pragma unroll
    for (int g = 0; g < 16; ++g) {
        const int row = g * 4 + wave;
        *reinterpret_cast<float4*>(&tile[row * TT + lane * 4]) = v[g];
    }
    __syncthreads();   // x tile 0 ready

    for (int k = 0; k < TILES; ++k) {
        const size_t toff = tstart + (size_t)k * TT;

        // -- issue prefetch of tile k+1 (overlaps everything below) --
        if (k + 1 < TILES) {
            #pragma unroll
            for (int g = 0; g < 16; ++g) {
                const int row = g * 4 + wave;
                v[g] = *reinterpret_cast<const float4*>(
                    x + bbase + toff + TT + (size_t)row * Tdim + lane * 4);
            }
        }

        // -- B fragments for this wave's two 32-t steps --
        // B[k][n]: n = ln, k = kb*16 + hi*8 + j ; col = wave*64 + st*32 + ln
        bf16x8 bfrag[2][4];
        #pragma unroll
        for (int st = 0; st < 2; ++st) {
            const int col = wave * 64 + st * 32 + ln;
            #pragma unroll
            for (int kb = 0; kb < 4; ++kb) {
                bf16x8 f;
                #pragma unroll
                for (int j = 0; j < 8; ++j)
                    f[j] = f2bf(tile[(kb * 16 + hi * 8 + j) * TT + col]);
                bfrag[st][kb] = f;
            }
        }
        __syncthreads();   // all frag reads done; tile becomes the out-tile

        // -- MFMA + epilogue into tile[o][col] --
        #pragma unroll
        for (int st = 0; st < 2; ++st) {
            const int col = wave * 64 + st * 32 + ln;
            #pragma unroll
            for (int ot = 0; ot < 2; ++ot) {
                f32x16 acc = bini[ot];
                #pragma unroll
                for (int kb = 0; kb < 4; ++kb)
                    acc = __builtin_amdgcn_mfma_f32_32x32x16_bf16(
                        afrag[ot][kb], bfrag[st][kb], acc, 0, 0, 0);
                #pragma unroll
                for (int r = 0; r < 16; ++r)
                    tile[(ot * 32 + (r & 3) + 8 * (r >> 2) + 4 * hi) * TT + col] = acc[r];
            }
        }
        __syncthreads();   // out tile complete

        // -- store out tile (1KB-row bursts), then rewrite same rows with x(k+1)
        //    (same-wave same-address DS ops are ordered; row sets per wave are
        //    disjoint, so no barrier needed between readback and rewrite) --
        #pragma unroll
        for (int g = 0; g < 16; ++g) {
            const int row = g * 4 + wave;
            const float4 o4 = *reinterpret_cast<const float4*>(&tile[row * TT + lane * 4]);
            *reinterpret_cast<float4*>(
                out + bbase + toff + (size_t)row * Tdim + lane * 4) = o4;
        }
        if (k + 1 < TILES) {
            #pragma unroll
            for (int g = 0; g < 16; ++g) {
                const int row = g * 4 + wave;
                *reinterpret_cast<float4*>(&tile[row * TT + lane * 4]) = v[g];
            }
        }
        __syncthreads();   // x tile k+1 ready
    }
}

extern "C" void kernel_launch(void* const* d_in, const int* in_sizes, int n_in,
                              void* d_out, int out_size, void* d_ws, size_t ws_size,
                              hipStream_t stream) {
    const float* x    = (const float*)d_in[0];   // [B, C, T]
    const int*   subj = (const int*)  d_in[1];   // [B]
    const float* W    = (const float*)d_in[2];   // [S, C, C]
    const float* bias = (const float*)d_in[3];   // [S, C]
    float*       out  = (float*)d_out;           // [B, C, T]

    const int B = in_sizes[1];                   // 128
    dim3 grid(Tdim / (TILES * TT), B);           // (4, 128) = 512 blocks = 2/CU
    dim3 block(BLOCK);
    hipLaunchKernelGGL(subject_layers_r8, grid, block, 0, stream,
                       x, subj, W, bias, out);
}

// Round 10
// 104.884 us; speedup vs baseline: 2.2478x; 2.2478x over previous
//
#include <hip/hip_runtime.h>
#include <hip/hip_bf16.h>

// SubjectLayers via bf16 MFMA 32x32x16: out[b,o,t] = sum_c W[s,o,c]*x[b,c,t] + b[s,o]
// B=128, C=64, T=8192, S=16. fp32 in/out, bf16 matrix cores.
//
// R9 = R6 (TT=256, 1KB-row bursts both directions; best known 105.3us)
//      with the LDS tile stored as bf16 (32 KB instead of 64+ KB):
//   - 4 blocks/CU co-resident (vs 2): deeper TLP hides each block's serial
//     load->compute->store phase chain, WITHOUT shrinking bursts (R7's mistake)
//   - x converted f32->bf16 once at staging (MFMA consumes bf16 anyway);
//     frag reads are direct u16 loads, no per-frag cvt
//   - out tile reuses the same 32 KB as bf16 (extra rounding ~0.027, total
//     absmax ~0.06 << 0.117 threshold); readback cvt bf16->f32, f32 stores
//   - no R8-style register prefetch buffers -> no scratch spill (R8 lesson:
//     WRITE_SIZE 1.99x was v[16] spill traffic)
//   - 2 barriers only: per-wave 64-col slices make st=0 epilogue writes
//     (cols w*64+0..31) disjoint from st=1 frag reads (cols w*64+32..63);
//     same-wave DS ordering covers the rest.

typedef __attribute__((ext_vector_type(8))) short  bf16x8;   // 4 VGPRs
typedef __attribute__((ext_vector_type(16))) float f32x16;   // 16 VGPRs

namespace {
constexpr int Cdim  = 64;
constexpr int Tdim  = 8192;
constexpr int TT    = 256;        // t per block tile
constexpr int BLOCK = 256;        // 4 waves
}

static __device__ __forceinline__ unsigned short f2bfu(float f) {
    return __builtin_bit_cast(unsigned short, __float2bfloat16(f));
}
static __device__ __forceinline__ float bf2f(unsigned short u) {
    const unsigned int v = ((unsigned int)u) << 16;
    return __builtin_bit_cast(float, v);
}

__global__ __launch_bounds__(BLOCK, 4)
void subject_layers_r9(const float* __restrict__ x,
                       const int*   __restrict__ subj,
                       const float* __restrict__ W,
                       const float* __restrict__ bias,
                       float*       __restrict__ out) {
    __shared__ unsigned short tile[Cdim * TT];   // 32 KB bf16; x-tile then out-tile

    const int b    = blockIdx.y;
    const int tb   = blockIdx.x;
    const int tid  = threadIdx.x;
    const int wave = tid >> 6;
    const int lane = tid & 63;
    const int hi   = lane >> 5;   // 0..1
    const int ln   = lane & 31;   // m/n index within 32-tile
    const int s    = subj[b];

    const size_t xbase = (size_t)b * Cdim * Tdim + (size_t)tb * TT;

    // ---- stage x tile as bf16: wave w owns rows g*4+w; one global instr =
    //      one row = 1KB contiguous; LDS write = 512B b64, conflict-free ----
    {
        float4 v[4];
        #pragma unroll
        for (int gg = 0; gg < 4; ++gg) {
            #pragma unroll
            for (int g = 0; g < 4; ++g) {
                const int row = (gg * 4 + g) * 4 + wave;
                v[g] = *reinterpret_cast<const float4*>(
                    x + xbase + (size_t)row * Tdim + lane * 4);
            }
            #pragma unroll
            for (int g = 0; g < 4; ++g) {
                const int row = (gg * 4 + g) * 4 + wave;
                ushort4 u;
                u.x = f2bfu(v[g].x); u.y = f2bfu(v[g].y);
                u.z = f2bfu(v[g].z); u.w = f2bfu(v[g].w);
                *reinterpret_cast<ushort4*>(&tile[row * TT + lane * 4]) = u;
            }
        }
    }

    // ---- A fragments: W[s] -> bf16 (overlaps staging; no dependency) ----
    // A[m][k]: m = ln, k = kb*16 + hi*8 + j  (mirrored with B -> k-perm cancels)
    bf16x8 afrag[2][4];
    const float* Wb = W + (size_t)s * Cdim * Cdim;
    #pragma unroll
    for (int ot = 0; ot < 2; ++ot) {
        #pragma unroll
        for (int kb = 0; kb < 4; ++kb) {
            const float* ap = Wb + (size_t)(ot * 32 + ln) * Cdim + kb * 16 + hi * 8;
            const float4 a0 = *reinterpret_cast<const float4*>(ap);
            const float4 a1 = *reinterpret_cast<const float4*>(ap + 4);
            bf16x8 f;
            f[0] = (short)f2bfu(a0.x); f[1] = (short)f2bfu(a0.y);
            f[2] = (short)f2bfu(a0.z); f[3] = (short)f2bfu(a0.w);
            f[4] = (short)f2bfu(a1.x); f[5] = (short)f2bfu(a1.y);
            f[6] = (short)f2bfu(a1.z); f[7] = (short)f2bfu(a1.w);
            afrag[ot][kb] = f;
        }
    }

    // ---- bias -> accumulator init ----
    // C/D: col = ln, row(reg r) = (r&3) + 8*(r>>2) + 4*hi   [m74/m101-verified]
    f32x16 bini[2];
    const float* bb = bias + (size_t)s * Cdim;
    #pragma unroll
    for (int ot = 0; ot < 2; ++ot)
        #pragma unroll
        for (int r = 0; r < 16; ++r)
            bini[ot][r] = bb[ot * 32 + (r & 3) + 8 * (r >> 2) + 4 * hi];

    __syncthreads();   // x tile ready

    // ---- per 32-t step: frag read -> MFMA -> epilogue write (bf16) ----
    // wave w's col slice [w*64, w*64+64): st=0 epi writes cols +0..31, st=1
    // frag reads cols +32..63 -> disjoint; same-wave DS ops are ordered.
    #pragma unroll
    for (int st = 0; st < 2; ++st) {
        const int col = wave * 64 + st * 32 + ln;

        // B[k][n]: n = ln, k = kb*16 + hi*8 + j (mirror of A); already bf16
        bf16x8 bfrag[4];
        #pragma unroll
        for (int kb = 0; kb < 4; ++kb) {
            bf16x8 f;
            #pragma unroll
            for (int j = 0; j < 8; ++j)
                f[j] = (short)tile[(kb * 16 + hi * 8 + j) * TT + col];
            bfrag[kb] = f;
        }

        #pragma unroll
        for (int ot = 0; ot < 2; ++ot) {
            f32x16 acc = bini[ot];
            #pragma unroll
            for (int kb = 0; kb < 4; ++kb)
                acc = __builtin_amdgcn_mfma_f32_32x32x16_bf16(
                    afrag[ot][kb], bfrag[kb], acc, 0, 0, 0);
            #pragma unroll
            for (int r = 0; r < 16; ++r)
                tile[(ot * 32 + (r & 3) + 8 * (r >> 2) + 4 * hi) * TT + col] =
                    f2bfu(acc[r]);
        }
    }

    __syncthreads();   // out tile complete

    // ---- cooperative store: readback bf16x4, cvt, 1KB-row f32 bursts ----
    #pragma unroll
    for (int g = 0; g < 16; ++g) {
        const int row = g * 4 + wave;
        const ushort4 u = *reinterpret_cast<const ushort4*>(&tile[row * TT + lane * 4]);
        float4 o4;
        o4.x = bf2f(u.x); o4.y = bf2f(u.y); o4.z = bf2f(u.z); o4.w = bf2f(u.w);
        *reinterpret_cast<float4*>(out + xbase + (size_t)row * Tdim + lane * 4) = o4;
    }
}

extern "C" void kernel_launch(void* const* d_in, const int* in_sizes, int n_in,
                              void* d_out, int out_size, void* d_ws, size_t ws_size,
                              hipStream_t stream) {
    const float* x    = (const float*)d_in[0];   // [B, C, T]
    const int*   subj = (const int*)  d_in[1];   // [B]
    const float* W    = (const float*)d_in[2];   // [S, C, C]
    const float* bias = (const float*)d_in[3];   // [S, C]
    float*       out  = (float*)d_out;           // [B, C, T]

    const int B = in_sizes[1];                   // 128
    dim3 grid(Tdim / TT, B);                     // (32, 128) = 4096 blocks
    dim3 block(BLOCK);
    hipLaunchKernelGGL(subject_layers_r9, grid, block, 0, stream,
                       x, subj, W, bias, out);
}

// Round 11
// 104.477 us; speedup vs baseline: 2.2565x; 1.0039x over previous
//
#include <hip/hip_runtime.h>
#include <hip/hip_bf16.h>

// SubjectLayers via bf16 MFMA 32x32x16: out[b,o,t] = sum_c W[s,o,c]*x[b,c,t] + b[s,o]
// B=128, C=64, T=8192, S=16. fp32 in/out, bf16 matrix cores.
//
// R10: minimal-phase kernel.
//  - x staged HBM->LDS via global_load_lds (width 16): 1KB row-bursts, zero
//    VGPR round trip, no ds_write issue. LDS = f32 [64][256] = 64KB, 2 blk/CU.
//  - ONE barrier. Frag reads from LDS (2-way, free), MFMA, then stores go
//    DIRECTLY from accumulators (R3 pattern: each store instr = 2 rows x 128B
//    full lines; measured clean WRITE in R3/R5). No out-LDS round trip.
//  - tests: was R6/R9's staging+epilogue phase chain the 20% BW thief, or is
//    the 64-row x 32KB-stride pattern an intrinsic ~5 TB/s wall?

typedef __attribute__((ext_vector_type(8))) short  bf16x8;   // 4 VGPRs
typedef __attribute__((ext_vector_type(16))) float f32x16;   // 16 VGPRs

namespace {
constexpr int Cdim  = 64;
constexpr int Tdim  = 8192;
constexpr int TT    = 256;        // t per block tile
constexpr int BLOCK = 256;        // 4 waves
}

static __device__ __forceinline__ short f2bf(float f) {
    return (short)__builtin_bit_cast(unsigned short, __float2bfloat16(f));
}

__global__ __launch_bounds__(BLOCK, 2)
void subject_layers_r10(const float* __restrict__ x,
                        const int*   __restrict__ subj,
                        const float* __restrict__ W,
                        const float* __restrict__ bias,
                        float*       __restrict__ out) {
    __shared__ float tile[Cdim * TT];   // 64 KB, x only (read-only after barrier)

    const int b    = blockIdx.y;
    const int tb   = blockIdx.x;
    const int tid  = threadIdx.x;
    const int wave = tid >> 6;
    const int lane = tid & 63;
    const int hi   = lane >> 5;   // 0..1
    const int ln   = lane & 31;   // m/n index within 32-tile
    const int s    = subj[b];

    const size_t xbase = (size_t)b * Cdim * Tdim + (size_t)tb * TT;

    // ---- stage x: wave w owns rows g*4+w; one global_load_lds = one 1KB row.
    //      LDS dest = wave-uniform row base + lane*16 (exactly the HW layout).
    #pragma unroll
    for (int g = 0; g < 16; ++g) {
        const int row = g * 4 + wave;
        __builtin_amdgcn_global_load_lds(
            (const __attribute__((address_space(1))) unsigned int*)
                (x + xbase + (size_t)row * Tdim + lane * 4),
            (__attribute__((address_space(3))) unsigned int*)
                (&tile[row * TT]),
            16, 0, 0);
    }

    // ---- A fragments: W[s] -> bf16 (independent of staging) ----
    // A[m][k]: m = ln, k = kb*16 + hi*8 + j  (mirrored with B -> k-perm cancels)
    bf16x8 afrag[2][4];
    const float* Wb = W + (size_t)s * Cdim * Cdim;
    #pragma unroll
    for (int ot = 0; ot < 2; ++ot) {
        #pragma unroll
        for (int kb = 0; kb < 4; ++kb) {
            const float* ap = Wb + (size_t)(ot * 32 + ln) * Cdim + kb * 16 + hi * 8;
            const float4 a0 = *reinterpret_cast<const float4*>(ap);
            const float4 a1 = *reinterpret_cast<const float4*>(ap + 4);
            bf16x8 f;
            f[0] = f2bf(a0.x); f[1] = f2bf(a0.y); f[2] = f2bf(a0.z); f[3] = f2bf(a0.w);
            f[4] = f2bf(a1.x); f[5] = f2bf(a1.y); f[6] = f2bf(a1.z); f[7] = f2bf(a1.w);
            afrag[ot][kb] = f;
        }
    }

    // ---- bias -> accumulator init ----
    // C/D: col = ln, row(reg r) = (r&3) + 8*(r>>2) + 4*hi   [m74/m101-verified]
    f32x16 bini[2];
    const float* bb = bias + (size_t)s * Cdim;
    #pragma unroll
    for (int ot = 0; ot < 2; ++ot)
        #pragma unroll
        for (int r = 0; r < 16; ++r)
            bini[ot][r] = bb[ot * 32 + (r & 3) + 8 * (r >> 2) + 4 * hi];

    __syncthreads();   // x tile ready (compiler drains vmcnt before barrier)

    // ---- per 32-t step: frag read -> MFMA -> direct acc stores ----
    float* ob = out + xbase;
    #pragma unroll
    for (int st = 0; st < 2; ++st) {
        const int col = wave * 64 + st * 32 + ln;

        // B[k][n]: n = ln, k = kb*16 + hi*8 + j (mirror of A)
        // LDS read: 32 consecutive f32 per hi-half -> banks 0..31, 2-way (free)
        bf16x8 bfrag[4];
        #pragma unroll
        for (int kb = 0; kb < 4; ++kb) {
            bf16x8 f;
            #pragma unroll
            for (int j = 0; j < 8; ++j)
                f[j] = f2bf(tile[(kb * 16 + hi * 8 + j) * TT + col]);
            bfrag[kb] = f;
        }

        #pragma unroll
        for (int ot = 0; ot < 2; ++ot) {
            f32x16 acc = bini[ot];
            #pragma unroll
            for (int kb = 0; kb < 4; ++kb)
                acc = __builtin_amdgcn_mfma_f32_32x32x16_bf16(
                    afrag[ot][kb], bfrag[kb], acc, 0, 0, 0);
            // store instr r: lanes 0-31 -> row R cols 0..31 (128B line),
            // lanes 32-63 -> row R+4 same cols (128B line). Full lines, no nt.
            #pragma unroll
            for (int r = 0; r < 16; ++r)
                ob[(size_t)(ot * 32 + (r & 3) + 8 * (r >> 2) + 4 * hi) * Tdim + col]
                    = acc[r];
        }
    }
}

extern "C" void kernel_launch(void* const* d_in, const int* in_sizes, int n_in,
                              void* d_out, int out_size, void* d_ws, size_t ws_size,
                              hipStream_t stream) {
    const float* x    = (const float*)d_in[0];   // [B, C, T]
    const int*   subj = (const int*)  d_in[1];   // [B]
    const float* W    = (const float*)d_in[2];   // [S, C, C]
    const float* bias = (const float*)d_in[3];   // [S, C]
    float*       out  = (float*)d_out;           // [B, C, T]

    const int B = in_sizes[1];                   // 128
    dim3 grid(Tdim / TT, B);                     // (32, 128) = 4096 blocks
    dim3 block(BLOCK);
    hipLaunchKernelGGL(subject_layers_r10, grid, block, 0, stream,
                       x, subj, W, bias, out);
}